// Round 5
// baseline (638.113 us; speedup 1.0000x reference)
//
#include <hip/hip_runtime.h>
#include <stdint.h>

// out[index[i]] += value[i], duplicates accumulate. N = 2^24 table, M = 2^25 updates.
// Atomic-free counting sort (global atomicAdd is capped ~26 G/s on gfx950).
// Round-5 insight: pair order within a bucket is irrelevant (integer adds commute),
// so binning needs NO LDS sort / binary search / stable ranks — just an LDS cursor
// per bucket seeded from the scanned per-chunk histogram, and scattered plain
// stores (merged memory-side in the 256 MB MALL; pairs region = 134 MB fits).

#define LOGSLICE  14
#define SLICE     (1 << LOGSLICE)     // 16384 table entries per bucket (64 KiB LDS)
#define NB        1024                // buckets = 2^24 / 2^14
#define CHUNK     16384               // updates per count/bin block
#define B_THR     256

// ---------- K1: per-chunk bucket histogram ----------
__global__ __launch_bounds__(256) void ip_count(const int4* __restrict__ index4,
                                                uint32_t* __restrict__ gcnt) {
    __shared__ uint32_t cnt[NB];
    const int t = threadIdx.x, c = blockIdx.x;
    for (int i = t; i < NB; i += B_THR) cnt[i] = 0;
    __syncthreads();
    const int base4 = c * (CHUNK / 4);
#pragma unroll
    for (int k = 0; k < CHUNK / 4 / B_THR; ++k) {
        int4 id = index4[base4 + t + k * B_THR];
        atomicAdd(&cnt[((uint32_t)id.x) >> LOGSLICE], 1u);
        atomicAdd(&cnt[((uint32_t)id.y) >> LOGSLICE], 1u);
        atomicAdd(&cnt[((uint32_t)id.z) >> LOGSLICE], 1u);
        atomicAdd(&cnt[((uint32_t)id.w) >> LOGSLICE], 1u);
    }
    __syncthreads();
    for (int i = t; i < NB; i += B_THR)
        gcnt[(size_t)c * NB + i] = cnt[i];
}

// ---------- K2: exclusive scan over chunks, per bucket (in place) ----------
__global__ __launch_bounds__(256) void ip_scan_chunks(uint32_t* __restrict__ gcnt,
                                                      uint32_t* __restrict__ btotal, int B) {
    __shared__ uint32_t tmp[B_THR];
    const int t = threadIdx.x, b = blockIdx.x;
    uint32_t running = 0;
    for (int r = 0; r < B; r += B_THR) {
        const size_t slot = (size_t)(r + t) * NB + b;
        uint32_t v = gcnt[slot];
        tmp[t] = v; __syncthreads();
        for (int off = 1; off < B_THR; off <<= 1) {
            uint32_t u = (t >= off) ? tmp[t - off] : 0; __syncthreads();
            tmp[t] += u; __syncthreads();
        }
        uint32_t incl = tmp[t], tot = tmp[B_THR - 1];
        gcnt[slot] = running + (incl - v);
        running += tot;
        __syncthreads();
    }
    if (t == 0) btotal[b] = running;
}

// ---------- K3: exclusive scan over buckets ----------
__global__ __launch_bounds__(1024) void ip_scan_buckets(const uint32_t* __restrict__ btotal,
                                                        uint32_t* __restrict__ bbase) {
    __shared__ uint32_t tmp[NB];
    const int t = threadIdx.x;
    uint32_t v = btotal[t];
    tmp[t] = v; __syncthreads();
    for (int off = 1; off < NB; off <<= 1) {
        uint32_t u = (t >= off) ? tmp[t - off] : 0; __syncthreads();
        tmp[t] += u; __syncthreads();
    }
    bbase[t] = tmp[t] - v;
}

// ---------- K4: bin into bucket-contiguous regions (no sort, no search) ----------
__global__ __launch_bounds__(256) void ip_bin(const int4* __restrict__ index4,
                                              const int4* __restrict__ value4,
                                              const uint32_t* __restrict__ gcnt,
                                              const uint32_t* __restrict__ bbase,
                                              uint32_t* __restrict__ pairs) {
    __shared__ uint32_t cur[NB];   // 4 KiB only
    const int t = threadIdx.x, c = blockIdx.x;
    for (int i = t; i < NB; i += B_THR)
        cur[i] = bbase[i] + gcnt[(size_t)c * NB + i];
    __syncthreads();
    const int base4 = c * (CHUNK / 4);
#pragma unroll
    for (int k = 0; k < CHUNK / 4 / B_THR; ++k) {
        int4 id = index4[base4 + t + k * B_THR];
        int4 v  = value4[base4 + t + k * B_THR];
#define DO(cc)                                                                   \
        {                                                                        \
            uint32_t ix  = (uint32_t)id.cc;                                      \
            uint32_t pos = atomicAdd(&cur[ix >> LOGSLICE], 1u);                  \
            pairs[pos] = (((uint32_t)v.cc) << LOGSLICE) | (ix & (SLICE - 1));    \
        }
        DO(x) DO(y) DO(z) DO(w)
#undef DO
    }
}

// ---------- K5: per-slice LDS accumulate, out = input + acc ----------
__global__ __launch_bounds__(512) void ip_accumulate(const uint32_t* __restrict__ pairs,
                                                     const uint32_t* __restrict__ btotal,
                                                     const uint32_t* __restrict__ bbase,
                                                     const int4* __restrict__ input4,
                                                     int4* __restrict__ out4) {
    __shared__ uint32_t acc[SLICE];    // 64 KiB
    const int b = blockIdx.x, t = threadIdx.x;
    for (int j = t; j < SLICE; j += 512) acc[j] = 0;
    __syncthreads();

    const uint32_t beg = bbase[b];
    const uint32_t cnt = btotal[b];

    // alignment-safe vectorized replay: scalar head to 16B, uint4 body, scalar tail
    uint32_t head = (4u - (beg & 3u)) & 3u;
    if (head > cnt) head = cnt;
    if (t < (int)head) {
        uint32_t pk = pairs[beg + t];
        atomicAdd(&acc[pk & (SLICE - 1)], pk >> LOGSLICE);
    }
    const uint32_t rem = cnt - head;
    const uint32_t n4  = rem >> 2;
    const uint32_t* __restrict__ p = pairs + beg + head;
    const uint4* __restrict__ p4 = (const uint4*)p;
    for (uint32_t j = t; j < n4; j += 512) {
        uint4 pk = p4[j];
        atomicAdd(&acc[pk.x & (SLICE - 1)], pk.x >> LOGSLICE);
        atomicAdd(&acc[pk.y & (SLICE - 1)], pk.y >> LOGSLICE);
        atomicAdd(&acc[pk.z & (SLICE - 1)], pk.z >> LOGSLICE);
        atomicAdd(&acc[pk.w & (SLICE - 1)], pk.w >> LOGSLICE);
    }
    for (uint32_t j = (n4 << 2) + t; j < rem; j += 512) {
        uint32_t pk = p[j];
        atomicAdd(&acc[pk & (SLICE - 1)], pk >> LOGSLICE);
    }
    __syncthreads();

    const int base4 = b * (SLICE / 4);
    for (int j = t; j < SLICE / 4; j += 512) {
        int4 in = input4[base4 + j];
        in.x += (int)acc[j * 4 + 0];
        in.y += (int)acc[j * 4 + 1];
        in.z += (int)acc[j * 4 + 2];
        in.w += (int)acc[j * 4 + 3];
        out4[base4 + j] = in;
    }
}

// ---------- fallback: direct atomics ----------
__global__ void ip_copy_kernel(const int4* __restrict__ in, int4* __restrict__ out, int n4) {
    int stride = gridDim.x * blockDim.x;
    for (int i = blockIdx.x * blockDim.x + threadIdx.x; i < n4; i += stride)
        out[i] = in[i];
}
__global__ void ip_scatter1_kernel(const int* __restrict__ index, const int* __restrict__ value,
                                   int* __restrict__ out, int m) {
    int stride = gridDim.x * blockDim.x;
    for (int i = blockIdx.x * blockDim.x + threadIdx.x; i < m; i += stride)
        atomicAdd(&out[index[i]], value[i]);
}

extern "C" void kernel_launch(void* const* d_in, const int* in_sizes, int n_in,
                              void* d_out, int out_size, void* d_ws, size_t ws_size,
                              hipStream_t stream) {
    const int* input = (const int*)d_in[0];
    const int* index = (const int*)d_in[1];
    const int* value = (const int*)d_in[2];
    int* out = (int*)d_out;

    const int N = in_sizes[0];
    const int M = in_sizes[1];
    const int B = M / CHUNK;   // chunks = count/bin blocks (2048)

    const size_t gcnt_bytes = (size_t)B * NB * sizeof(uint32_t);      // 8 MB
    const size_t tot_bytes  = NB * sizeof(uint32_t);
    const size_t need = gcnt_bytes + 2 * tot_bytes + (size_t)M * sizeof(uint32_t);

    const bool ok = (N == NB * SLICE) && (M % CHUNK == 0) && (B % B_THR == 0) &&
                    (ws_size >= need);

    if (ok) {
        uint32_t* gcnt   = (uint32_t*)d_ws;
        uint32_t* btotal = (uint32_t*)((char*)d_ws + gcnt_bytes);
        uint32_t* bbase  = btotal + NB;
        uint32_t* pairs  = bbase + NB;

        ip_count<<<B, B_THR, 0, stream>>>((const int4*)index, gcnt);
        ip_scan_chunks<<<NB, B_THR, 0, stream>>>(gcnt, btotal, B);
        ip_scan_buckets<<<1, NB, 0, stream>>>(btotal, bbase);
        ip_bin<<<B, B_THR, 0, stream>>>((const int4*)index, (const int4*)value,
                                        gcnt, bbase, pairs);
        ip_accumulate<<<NB, 512, 0, stream>>>(pairs, btotal, bbase,
                                              (const int4*)input, (int4*)out);
    } else {
        ip_copy_kernel<<<2048, 256, 0, stream>>>((const int4*)input, (int4*)d_out, N / 4);
        ip_scatter1_kernel<<<2048, 256, 0, stream>>>(index, value, out, M);
    }
}

// Round 6
// 303.503 us; speedup vs baseline: 2.1025x; 2.1025x over previous
//
#include <hip/hip_runtime.h>
#include <stdint.h>

// out[index[i]] += value[i], duplicates accumulate. N = 2^24 table, M = 2^25 updates.
// Counting sort, no global atomics (capped ~26 G/s on gfx950, rounds 1-3).
// Round-6: bin = LDS-staged bucket grouping (round 4) WITHOUT the binary search:
// store bucket-id per staged slot (uint16), write-out computes the global address
// directly -> bucket-contiguous coalesced runs (round 5 showed raw scattered 4B
// stores cost ~25B/op of partial-sector writeback: WRITE 843MB for 134MB of data).

#define LOGSLICE  14
#define SLICE     (1 << LOGSLICE)     // 16384 table entries per bucket (64 KiB acc)
#define NB        1024                // buckets = 2^24 / 2^14
#define CHUNK     8192                // updates per count/bin block
#define CNT_THR   256
#define BIN_THR   512
#define EPT       (CHUNK / 4 / BIN_THR)   // int4 loads per thread in bin = 4

// ---------- K1: per-chunk bucket histogram ----------
__global__ __launch_bounds__(256) void ip_count(const int4* __restrict__ index4,
                                                uint32_t* __restrict__ gcnt) {
    __shared__ uint32_t cnt[NB];
    const int t = threadIdx.x, c = blockIdx.x;
    for (int i = t; i < NB; i += CNT_THR) cnt[i] = 0;
    __syncthreads();
    const int base4 = c * (CHUNK / 4);
#pragma unroll
    for (int k = 0; k < CHUNK / 4 / CNT_THR; ++k) {
        int4 id = index4[base4 + t + k * CNT_THR];
        atomicAdd(&cnt[((uint32_t)id.x) >> LOGSLICE], 1u);
        atomicAdd(&cnt[((uint32_t)id.y) >> LOGSLICE], 1u);
        atomicAdd(&cnt[((uint32_t)id.z) >> LOGSLICE], 1u);
        atomicAdd(&cnt[((uint32_t)id.w) >> LOGSLICE], 1u);
    }
    __syncthreads();
    for (int i = t; i < NB; i += CNT_THR)
        gcnt[(size_t)c * NB + i] = cnt[i];
}

// ---------- K2: exclusive scan over chunks, per bucket (in place) ----------
__global__ __launch_bounds__(256) void ip_scan_chunks(uint32_t* __restrict__ gcnt,
                                                      uint32_t* __restrict__ btotal, int B) {
    __shared__ uint32_t tmp[CNT_THR];
    const int t = threadIdx.x, b = blockIdx.x;
    uint32_t running = 0;
    for (int r = 0; r < B; r += CNT_THR) {
        const size_t slot = (size_t)(r + t) * NB + b;
        uint32_t v = gcnt[slot];
        tmp[t] = v; __syncthreads();
        for (int off = 1; off < CNT_THR; off <<= 1) {
            uint32_t u = (t >= off) ? tmp[t - off] : 0; __syncthreads();
            tmp[t] += u; __syncthreads();
        }
        uint32_t incl = tmp[t], tot = tmp[CNT_THR - 1];
        gcnt[slot] = running + (incl - v);
        running += tot;
        __syncthreads();
    }
    if (t == 0) btotal[b] = running;
}

// ---------- K3: exclusive scan over buckets ----------
__global__ __launch_bounds__(1024) void ip_scan_buckets(const uint32_t* __restrict__ btotal,
                                                        uint32_t* __restrict__ bbase) {
    __shared__ uint32_t tmp[NB];
    const int t = threadIdx.x;
    uint32_t v = btotal[t];
    tmp[t] = v; __syncthreads();
    for (int off = 1; off < NB; off <<= 1) {
        uint32_t u = (t >= off) ? tmp[t - off] : 0; __syncthreads();
        tmp[t] += u; __syncthreads();
    }
    bbase[t] = tmp[t] - v;
}

// ---------- K4: bin into bucket-contiguous runs via LDS staging ----------
__global__ __launch_bounds__(512) void ip_bin(const int4* __restrict__ index4,
                                              const int4* __restrict__ value4,
                                              const uint32_t* __restrict__ gcnt,
                                              const uint32_t* __restrict__ bbase,
                                              uint32_t* __restrict__ pairs) {
    __shared__ uint32_t cur[NB];        // counts -> lstart (then read-only)
    __shared__ uint32_t gbase[NB];      // global run start per bucket for this chunk
    __shared__ uint32_t spk[CHUNK];     // staged payload, grouped by bucket (32 KiB)
    __shared__ uint16_t sbid[CHUNK];    // bucket id per staged slot (16 KiB)
    __shared__ uint32_t tmp[BIN_THR];
    const int t = threadIdx.x, c = blockIdx.x;

    for (int i = t; i < NB; i += BIN_THR) cur[i] = 0;
    __syncthreads();

    const int base4 = c * (CHUNK / 4);
    int4 idx[EPT], val[EPT];
#pragma unroll
    for (int k = 0; k < EPT; ++k) {
        idx[k] = index4[base4 + t + k * BIN_THR];
        val[k] = value4[base4 + t + k * BIN_THR];
    }
    uint32_t lrank[EPT * 4];
#pragma unroll
    for (int k = 0; k < EPT; ++k) {
        lrank[k * 4 + 0] = atomicAdd(&cur[((uint32_t)idx[k].x) >> LOGSLICE], 1u);
        lrank[k * 4 + 1] = atomicAdd(&cur[((uint32_t)idx[k].y) >> LOGSLICE], 1u);
        lrank[k * 4 + 2] = atomicAdd(&cur[((uint32_t)idx[k].z) >> LOGSLICE], 1u);
        lrank[k * 4 + 3] = atomicAdd(&cur[((uint32_t)idx[k].w) >> LOGSLICE], 1u);
    }
    __syncthreads();

    // gbase[i] = bucket base + this chunk's exclusive offset within bucket
    for (int i = t; i < NB; i += BIN_THR)
        gbase[i] = bbase[i] + gcnt[(size_t)c * NB + i];

    // exclusive scan of per-bucket counts -> lstart (2 buckets per thread)
    uint32_t c0 = cur[t * 2 + 0], c1 = cur[t * 2 + 1];
    uint32_t s = c0 + c1;
    tmp[t] = s; __syncthreads();
    for (int off = 1; off < BIN_THR; off <<= 1) {
        uint32_t u = (t >= off) ? tmp[t - off] : 0; __syncthreads();
        tmp[t] += u; __syncthreads();
    }
    uint32_t ex = tmp[t] - s;
    cur[t * 2 + 0] = ex;
    cur[t * 2 + 1] = ex + c0;
    __syncthreads();

    // place: slot = lstart[b] + lrank  (cur NOT modified: stays lstart)
#define PLACE(k, cc, e)                                                          \
    {                                                                            \
        uint32_t ix = (uint32_t)idx[k].cc;                                       \
        uint32_t b_ = ix >> LOGSLICE;                                            \
        uint32_t p_ = cur[b_] + lrank[e];                                        \
        spk[p_]  = (((uint32_t)val[k].cc) << LOGSLICE) | (ix & (SLICE - 1));     \
        sbid[p_] = (uint16_t)b_;                                                 \
    }
#pragma unroll
    for (int k = 0; k < EPT; ++k) {
        PLACE(k, x, k * 4 + 0) PLACE(k, y, k * 4 + 1)
        PLACE(k, z, k * 4 + 2) PLACE(k, w, k * 4 + 3)
    }
#undef PLACE
    __syncthreads();

    // write out: consecutive j within a bucket -> consecutive global addresses
#pragma unroll
    for (int k = 0; k < CHUNK / BIN_THR; ++k) {
        int j = t + k * BIN_THR;
        uint32_t b_ = sbid[j];
        pairs[gbase[b_] + ((uint32_t)j - cur[b_])] = spk[j];
    }
}

// ---------- K5: per-slice LDS accumulate, out = input + acc ----------
__global__ __launch_bounds__(512) void ip_accumulate(const uint32_t* __restrict__ pairs,
                                                     const uint32_t* __restrict__ btotal,
                                                     const uint32_t* __restrict__ bbase,
                                                     const int4* __restrict__ input4,
                                                     int4* __restrict__ out4) {
    __shared__ uint32_t acc[SLICE];    // 64 KiB
    const int b = blockIdx.x, t = threadIdx.x;
    for (int j = t; j < SLICE; j += 512) acc[j] = 0;
    __syncthreads();

    const uint32_t beg = bbase[b];
    const uint32_t cnt = btotal[b];

    uint32_t head = (4u - (beg & 3u)) & 3u;
    if (head > cnt) head = cnt;
    if (t < (int)head) {
        uint32_t pk = pairs[beg + t];
        atomicAdd(&acc[pk & (SLICE - 1)], pk >> LOGSLICE);
    }
    const uint32_t rem = cnt - head;
    const uint32_t n4  = rem >> 2;
    const uint32_t* __restrict__ p = pairs + beg + head;
    const uint4* __restrict__ p4 = (const uint4*)p;
    for (uint32_t j = t; j < n4; j += 512) {
        uint4 pk = p4[j];
        atomicAdd(&acc[pk.x & (SLICE - 1)], pk.x >> LOGSLICE);
        atomicAdd(&acc[pk.y & (SLICE - 1)], pk.y >> LOGSLICE);
        atomicAdd(&acc[pk.z & (SLICE - 1)], pk.z >> LOGSLICE);
        atomicAdd(&acc[pk.w & (SLICE - 1)], pk.w >> LOGSLICE);
    }
    for (uint32_t j = (n4 << 2) + t; j < rem; j += 512) {
        uint32_t pk = p[j];
        atomicAdd(&acc[pk & (SLICE - 1)], pk >> LOGSLICE);
    }
    __syncthreads();

    const int base4 = b * (SLICE / 4);
    for (int j = t; j < SLICE / 4; j += 512) {
        int4 in = input4[base4 + j];
        in.x += (int)acc[j * 4 + 0];
        in.y += (int)acc[j * 4 + 1];
        in.z += (int)acc[j * 4 + 2];
        in.w += (int)acc[j * 4 + 3];
        out4[base4 + j] = in;
    }
}

// ---------- fallback: direct atomics ----------
__global__ void ip_copy_kernel(const int4* __restrict__ in, int4* __restrict__ out, int n4) {
    int stride = gridDim.x * blockDim.x;
    for (int i = blockIdx.x * blockDim.x + threadIdx.x; i < n4; i += stride)
        out[i] = in[i];
}
__global__ void ip_scatter1_kernel(const int* __restrict__ index, const int* __restrict__ value,
                                   int* __restrict__ out, int m) {
    int stride = gridDim.x * blockDim.x;
    for (int i = blockIdx.x * blockDim.x + threadIdx.x; i < m; i += stride)
        atomicAdd(&out[index[i]], value[i]);
}

extern "C" void kernel_launch(void* const* d_in, const int* in_sizes, int n_in,
                              void* d_out, int out_size, void* d_ws, size_t ws_size,
                              hipStream_t stream) {
    const int* input = (const int*)d_in[0];
    const int* index = (const int*)d_in[1];
    const int* value = (const int*)d_in[2];
    int* out = (int*)d_out;

    const int N = in_sizes[0];
    const int M = in_sizes[1];
    const int B = M / CHUNK;   // chunks (4096)

    const size_t gcnt_bytes = (size_t)B * NB * sizeof(uint32_t);      // 16 MB
    const size_t tot_bytes  = NB * sizeof(uint32_t);
    const size_t need = gcnt_bytes + 2 * tot_bytes + (size_t)M * sizeof(uint32_t);

    const bool ok = (N == NB * SLICE) && (M % CHUNK == 0) && (B % CNT_THR == 0) &&
                    (ws_size >= need);

    if (ok) {
        uint32_t* gcnt   = (uint32_t*)d_ws;
        uint32_t* btotal = (uint32_t*)((char*)d_ws + gcnt_bytes);
        uint32_t* bbase  = btotal + NB;
        uint32_t* pairs  = bbase + NB;

        ip_count<<<B, CNT_THR, 0, stream>>>((const int4*)index, gcnt);
        ip_scan_chunks<<<NB, CNT_THR, 0, stream>>>(gcnt, btotal, B);
        ip_scan_buckets<<<1, NB, 0, stream>>>(btotal, bbase);
        ip_bin<<<B, BIN_THR, 0, stream>>>((const int4*)index, (const int4*)value,
                                          gcnt, bbase, pairs);
        ip_accumulate<<<NB, 512, 0, stream>>>(pairs, btotal, bbase,
                                              (const int4*)input, (int4*)out);
    } else {
        ip_copy_kernel<<<2048, 256, 0, stream>>>((const int4*)input, (int4*)d_out, N / 4);
        ip_scatter1_kernel<<<2048, 256, 0, stream>>>(index, value, out, M);
    }
}

// Round 7
// 288.694 us; speedup vs baseline: 2.2103x; 1.0513x over previous
//
#include <hip/hip_runtime.h>
#include <stdint.h>

// out[index[i]] += value[i], duplicates accumulate. N = 2^24 table, M = 2^25 updates.
// Counting sort, no global atomics (capped ~26 G/s on gfx950, rounds 1-3).
// Round-7: ip_bin LDS diet (52.03 KB -> 3 blocks/CU): gbase folded into cur
// (write-out uses doff[b] = gbase[b]-lstart[b], computed in place), block scan
// replaced by wave __shfl_up scan (no tmp[], ~30 fewer barriers).
// ip_accumulate: 1024 threads (32 waves/CU at 2 blocks/CU) for LDS-atomic latency hiding.

#define LOGSLICE  14
#define SLICE     (1 << LOGSLICE)     // 16384 table entries per bucket (64 KiB acc)
#define NB        1024                // buckets = 2^24 / 2^14
#define CHUNK     8192                // updates per count/bin block
#define CNT_THR   256
#define BIN_THR   512
#define EPT       (CHUNK / 4 / BIN_THR)   // int4 loads per thread in bin = 4

// ---------- K1: per-chunk bucket histogram ----------
__global__ __launch_bounds__(256) void ip_count(const int4* __restrict__ index4,
                                                uint32_t* __restrict__ gcnt) {
    __shared__ uint32_t cnt[NB];
    const int t = threadIdx.x, c = blockIdx.x;
    for (int i = t; i < NB; i += CNT_THR) cnt[i] = 0;
    __syncthreads();
    const int base4 = c * (CHUNK / 4);
#pragma unroll
    for (int k = 0; k < CHUNK / 4 / CNT_THR; ++k) {
        int4 id = index4[base4 + t + k * CNT_THR];
        atomicAdd(&cnt[((uint32_t)id.x) >> LOGSLICE], 1u);
        atomicAdd(&cnt[((uint32_t)id.y) >> LOGSLICE], 1u);
        atomicAdd(&cnt[((uint32_t)id.z) >> LOGSLICE], 1u);
        atomicAdd(&cnt[((uint32_t)id.w) >> LOGSLICE], 1u);
    }
    __syncthreads();
    for (int i = t; i < NB; i += CNT_THR)
        gcnt[(size_t)c * NB + i] = cnt[i];
}

// ---------- K2: exclusive scan over chunks, per bucket (in place) ----------
__global__ __launch_bounds__(256) void ip_scan_chunks(uint32_t* __restrict__ gcnt,
                                                      uint32_t* __restrict__ btotal, int B) {
    __shared__ uint32_t tmp[CNT_THR];
    const int t = threadIdx.x, b = blockIdx.x;
    uint32_t running = 0;
    for (int r = 0; r < B; r += CNT_THR) {
        const size_t slot = (size_t)(r + t) * NB + b;
        uint32_t v = gcnt[slot];
        tmp[t] = v; __syncthreads();
        for (int off = 1; off < CNT_THR; off <<= 1) {
            uint32_t u = (t >= off) ? tmp[t - off] : 0; __syncthreads();
            tmp[t] += u; __syncthreads();
        }
        uint32_t incl = tmp[t], tot = tmp[CNT_THR - 1];
        gcnt[slot] = running + (incl - v);
        running += tot;
        __syncthreads();
    }
    if (t == 0) btotal[b] = running;
}

// ---------- K3: exclusive scan over buckets ----------
__global__ __launch_bounds__(1024) void ip_scan_buckets(const uint32_t* __restrict__ btotal,
                                                        uint32_t* __restrict__ bbase) {
    __shared__ uint32_t tmp[NB];
    const int t = threadIdx.x;
    uint32_t v = btotal[t];
    tmp[t] = v; __syncthreads();
    for (int off = 1; off < NB; off <<= 1) {
        uint32_t u = (t >= off) ? tmp[t - off] : 0; __syncthreads();
        tmp[t] += u; __syncthreads();
    }
    bbase[t] = tmp[t] - v;
}

// ---------- K4: bin into bucket-contiguous runs via LDS staging ----------
__global__ __launch_bounds__(512) void ip_bin(const int4* __restrict__ index4,
                                              const int4* __restrict__ value4,
                                              const uint32_t* __restrict__ gcnt,
                                              const uint32_t* __restrict__ bbase,
                                              uint32_t* __restrict__ pairs) {
    __shared__ uint32_t cur[NB];        // counts -> lstart -> doff (reused in place)
    __shared__ uint32_t spk[CHUNK];     // staged payload, grouped by bucket (32 KiB)
    __shared__ uint16_t sbid[CHUNK];    // bucket id per staged slot (16 KiB)
    __shared__ uint32_t wsum[BIN_THR / 64];
    const int t = threadIdx.x, c = blockIdx.x;
    const int lane = t & 63, w = t >> 6;

    cur[t * 2 + 0] = 0;
    cur[t * 2 + 1] = 0;
    __syncthreads();

    const int base4 = c * (CHUNK / 4);
    int4 idx[EPT], val[EPT];
#pragma unroll
    for (int k = 0; k < EPT; ++k) {
        idx[k] = index4[base4 + t + k * BIN_THR];
        val[k] = value4[base4 + t + k * BIN_THR];
    }
    uint32_t lrank[EPT * 4];
#pragma unroll
    for (int k = 0; k < EPT; ++k) {
        lrank[k * 4 + 0] = atomicAdd(&cur[((uint32_t)idx[k].x) >> LOGSLICE], 1u);
        lrank[k * 4 + 1] = atomicAdd(&cur[((uint32_t)idx[k].y) >> LOGSLICE], 1u);
        lrank[k * 4 + 2] = atomicAdd(&cur[((uint32_t)idx[k].z) >> LOGSLICE], 1u);
        lrank[k * 4 + 3] = atomicAdd(&cur[((uint32_t)idx[k].w) >> LOGSLICE], 1u);
    }
    __syncthreads();

    // exclusive scan of per-bucket counts -> lstart (2 buckets/thread), wave shfl scan
    uint32_t c0 = cur[t * 2 + 0], c1 = cur[t * 2 + 1];
    uint32_t s = c0 + c1;
    uint32_t incl = s;
#pragma unroll
    for (int off = 1; off < 64; off <<= 1) {
        uint32_t u = __shfl_up(incl, off);
        if (lane >= off) incl += u;
    }
    if (lane == 63) wsum[w] = incl;
    __syncthreads();
    uint32_t woff = 0;
    for (int i = 0; i < w; ++i) woff += wsum[i];
    uint32_t ex = woff + incl - s;
    cur[t * 2 + 0] = ex;
    cur[t * 2 + 1] = ex + c0;
    __syncthreads();

    // place: slot = lstart[b] + lrank
#define PLACE(k, cc, e)                                                          \
    {                                                                            \
        uint32_t ix = (uint32_t)idx[k].cc;                                       \
        uint32_t b_ = ix >> LOGSLICE;                                            \
        uint32_t p_ = cur[b_] + lrank[e];                                        \
        spk[p_]  = (((uint32_t)val[k].cc) << LOGSLICE) | (ix & (SLICE - 1));     \
        sbid[p_] = (uint16_t)b_;                                                 \
    }
#pragma unroll
    for (int k = 0; k < EPT; ++k) {
        PLACE(k, x, k * 4 + 0) PLACE(k, y, k * 4 + 1)
        PLACE(k, z, k * 4 + 2) PLACE(k, w, k * 4 + 3)
    }
#undef PLACE
    __syncthreads();

    // cur[b] := doff[b] = bbase[b] + chunk_off[b] - lstart[b]  (addr = doff[b] + j)
#pragma unroll
    for (int r = 0; r < 2; ++r) {
        int i = t + r * BIN_THR;
        cur[i] = bbase[i] + gcnt[(size_t)c * NB + i] - cur[i];
    }
    __syncthreads();

    // write out: consecutive j within a bucket -> consecutive global addresses
#pragma unroll
    for (int k = 0; k < CHUNK / BIN_THR; ++k) {
        int j = t + k * BIN_THR;
        uint32_t b_ = sbid[j];
        pairs[cur[b_] + (uint32_t)j] = spk[j];
    }
}

// ---------- K5: per-slice LDS accumulate, out = input + acc ----------
__global__ __launch_bounds__(1024) void ip_accumulate(const uint32_t* __restrict__ pairs,
                                                      const uint32_t* __restrict__ btotal,
                                                      const uint32_t* __restrict__ bbase,
                                                      const int4* __restrict__ input4,
                                                      int4* __restrict__ out4) {
    __shared__ uint32_t acc[SLICE];    // 64 KiB
    const int b = blockIdx.x, t = threadIdx.x;
    for (int j = t; j < SLICE; j += 1024) acc[j] = 0;
    __syncthreads();

    const uint32_t beg = bbase[b];
    const uint32_t cnt = btotal[b];

    uint32_t head = (4u - (beg & 3u)) & 3u;
    if (head > cnt) head = cnt;
    if (t < (int)head) {
        uint32_t pk = pairs[beg + t];
        atomicAdd(&acc[pk & (SLICE - 1)], pk >> LOGSLICE);
    }
    const uint32_t rem = cnt - head;
    const uint32_t n4  = rem >> 2;
    const uint32_t* __restrict__ p = pairs + beg + head;
    const uint4* __restrict__ p4 = (const uint4*)p;
    for (uint32_t j = t; j < n4; j += 1024) {
        uint4 pk = p4[j];
        atomicAdd(&acc[pk.x & (SLICE - 1)], pk.x >> LOGSLICE);
        atomicAdd(&acc[pk.y & (SLICE - 1)], pk.y >> LOGSLICE);
        atomicAdd(&acc[pk.z & (SLICE - 1)], pk.z >> LOGSLICE);
        atomicAdd(&acc[pk.w & (SLICE - 1)], pk.w >> LOGSLICE);
    }
    for (uint32_t j = (n4 << 2) + t; j < rem; j += 1024) {
        uint32_t pk = p[j];
        atomicAdd(&acc[pk & (SLICE - 1)], pk >> LOGSLICE);
    }
    __syncthreads();

    const int base4 = b * (SLICE / 4);
    for (int j = t; j < SLICE / 4; j += 1024) {
        int4 in = input4[base4 + j];
        in.x += (int)acc[j * 4 + 0];
        in.y += (int)acc[j * 4 + 1];
        in.z += (int)acc[j * 4 + 2];
        in.w += (int)acc[j * 4 + 3];
        out4[base4 + j] = in;
    }
}

// ---------- fallback: direct atomics ----------
__global__ void ip_copy_kernel(const int4* __restrict__ in, int4* __restrict__ out, int n4) {
    int stride = gridDim.x * blockDim.x;
    for (int i = blockIdx.x * blockDim.x + threadIdx.x; i < n4; i += stride)
        out[i] = in[i];
}
__global__ void ip_scatter1_kernel(const int* __restrict__ index, const int* __restrict__ value,
                                   int* __restrict__ out, int m) {
    int stride = gridDim.x * blockDim.x;
    for (int i = blockIdx.x * blockDim.x + threadIdx.x; i < m; i += stride)
        atomicAdd(&out[index[i]], value[i]);
}

extern "C" void kernel_launch(void* const* d_in, const int* in_sizes, int n_in,
                              void* d_out, int out_size, void* d_ws, size_t ws_size,
                              hipStream_t stream) {
    const int* input = (const int*)d_in[0];
    const int* index = (const int*)d_in[1];
    const int* value = (const int*)d_in[2];
    int* out = (int*)d_out;

    const int N = in_sizes[0];
    const int M = in_sizes[1];
    const int B = M / CHUNK;   // chunks (4096)

    const size_t gcnt_bytes = (size_t)B * NB * sizeof(uint32_t);      // 16 MB
    const size_t tot_bytes  = NB * sizeof(uint32_t);
    const size_t need = gcnt_bytes + 2 * tot_bytes + (size_t)M * sizeof(uint32_t);

    const bool ok = (N == NB * SLICE) && (M % CHUNK == 0) && (B % CNT_THR == 0) &&
                    (ws_size >= need);

    if (ok) {
        uint32_t* gcnt   = (uint32_t*)d_ws;
        uint32_t* btotal = (uint32_t*)((char*)d_ws + gcnt_bytes);
        uint32_t* bbase  = btotal + NB;
        uint32_t* pairs  = bbase + NB;

        ip_count<<<B, CNT_THR, 0, stream>>>((const int4*)index, gcnt);
        ip_scan_chunks<<<NB, CNT_THR, 0, stream>>>(gcnt, btotal, B);
        ip_scan_buckets<<<1, NB, 0, stream>>>(btotal, bbase);
        ip_bin<<<B, BIN_THR, 0, stream>>>((const int4*)index, (const int4*)value,
                                          gcnt, bbase, pairs);
        ip_accumulate<<<NB, 1024, 0, stream>>>(pairs, btotal, bbase,
                                               (const int4*)input, (int4*)out);
    } else {
        ip_copy_kernel<<<2048, 256, 0, stream>>>((const int4*)input, (int4*)d_out, N / 4);
        ip_scatter1_kernel<<<2048, 256, 0, stream>>>(index, value, out, M);
    }
}

// Round 8
// 237.418 us; speedup vs baseline: 2.6877x; 1.2160x over previous
//
#include <hip/hip_runtime.h>
#include <stdint.h>

// out[index[i]] += value[i], duplicates accumulate. N = 2^24 table, M = 2^25 updates.
// Counting sort, no global atomics (capped ~26 G/s on gfx950, rounds 1-3).
// Round-8: XCD-chunked block->chunk swizzle in ip_bin. Adjacent chunks write
// ADJACENT global segments per bucket; putting consecutive chunks on the SAME
// XCD (c = (bid&7)*(B/8) + bid>>3, round-robin dispatch heuristic) lets its L2
// merge the ~32B partial-line run writes before writeback (round 6/7: WRITE
// 247MB for 134MB payload). Same swizzle on accumulate's bucket mapping.

#define LOGSLICE  14
#define SLICE     (1 << LOGSLICE)     // 16384 table entries per bucket (64 KiB acc)
#define NB        1024                // buckets = 2^24 / 2^14
#define CHUNK     8192                // updates per count/bin block
#define CNT_THR   256
#define BIN_THR   512
#define EPT       (CHUNK / 4 / BIN_THR)   // int4 loads per thread in bin = 4

// ---------- K1: per-chunk bucket histogram ----------
__global__ __launch_bounds__(256) void ip_count(const int4* __restrict__ index4,
                                                uint32_t* __restrict__ gcnt) {
    __shared__ uint32_t cnt[NB];
    const int t = threadIdx.x, c = blockIdx.x;
    for (int i = t; i < NB; i += CNT_THR) cnt[i] = 0;
    __syncthreads();
    const int base4 = c * (CHUNK / 4);
#pragma unroll
    for (int k = 0; k < CHUNK / 4 / CNT_THR; ++k) {
        int4 id = index4[base4 + t + k * CNT_THR];
        atomicAdd(&cnt[((uint32_t)id.x) >> LOGSLICE], 1u);
        atomicAdd(&cnt[((uint32_t)id.y) >> LOGSLICE], 1u);
        atomicAdd(&cnt[((uint32_t)id.z) >> LOGSLICE], 1u);
        atomicAdd(&cnt[((uint32_t)id.w) >> LOGSLICE], 1u);
    }
    __syncthreads();
    for (int i = t; i < NB; i += CNT_THR)
        gcnt[(size_t)c * NB + i] = cnt[i];
}

// ---------- K2: exclusive scan over chunks, per bucket (in place) ----------
__global__ __launch_bounds__(256) void ip_scan_chunks(uint32_t* __restrict__ gcnt,
                                                      uint32_t* __restrict__ btotal, int B) {
    __shared__ uint32_t tmp[CNT_THR];
    const int t = threadIdx.x, b = blockIdx.x;
    uint32_t running = 0;
    for (int r = 0; r < B; r += CNT_THR) {
        const size_t slot = (size_t)(r + t) * NB + b;
        uint32_t v = gcnt[slot];
        tmp[t] = v; __syncthreads();
        for (int off = 1; off < CNT_THR; off <<= 1) {
            uint32_t u = (t >= off) ? tmp[t - off] : 0; __syncthreads();
            tmp[t] += u; __syncthreads();
        }
        uint32_t incl = tmp[t], tot = tmp[CNT_THR - 1];
        gcnt[slot] = running + (incl - v);
        running += tot;
        __syncthreads();
    }
    if (t == 0) btotal[b] = running;
}

// ---------- K3: exclusive scan over buckets ----------
__global__ __launch_bounds__(1024) void ip_scan_buckets(const uint32_t* __restrict__ btotal,
                                                        uint32_t* __restrict__ bbase) {
    __shared__ uint32_t tmp[NB];
    const int t = threadIdx.x;
    uint32_t v = btotal[t];
    tmp[t] = v; __syncthreads();
    for (int off = 1; off < NB; off <<= 1) {
        uint32_t u = (t >= off) ? tmp[t - off] : 0; __syncthreads();
        tmp[t] += u; __syncthreads();
    }
    bbase[t] = tmp[t] - v;
}

// ---------- K4: bin into bucket-contiguous runs via LDS staging ----------
__global__ __launch_bounds__(512) void ip_bin(const int4* __restrict__ index4,
                                              const int4* __restrict__ value4,
                                              const uint32_t* __restrict__ gcnt,
                                              const uint32_t* __restrict__ bbase,
                                              uint32_t* __restrict__ pairs) {
    __shared__ uint32_t cur[NB];        // counts -> lstart -> doff (reused in place)
    __shared__ uint32_t spk[CHUNK];     // staged payload, grouped by bucket (32 KiB)
    __shared__ uint16_t sbid[CHUNK];    // bucket id per staged slot (16 KiB)
    __shared__ uint32_t wsum[BIN_THR / 64];
    const int t = threadIdx.x;
    // XCD-chunked swizzle: consecutive chunks land on the same XCD's L2 so their
    // adjacent per-bucket run segments merge into full lines before writeback.
    const int c = (int)((blockIdx.x & 7) * (gridDim.x >> 3) + (blockIdx.x >> 3));
    const int lane = t & 63, w = t >> 6;

    cur[t * 2 + 0] = 0;
    cur[t * 2 + 1] = 0;
    __syncthreads();

    const int base4 = c * (CHUNK / 4);
    int4 idx[EPT], val[EPT];
#pragma unroll
    for (int k = 0; k < EPT; ++k) {
        idx[k] = index4[base4 + t + k * BIN_THR];
        val[k] = value4[base4 + t + k * BIN_THR];
    }
    uint32_t lrank[EPT * 4];
#pragma unroll
    for (int k = 0; k < EPT; ++k) {
        lrank[k * 4 + 0] = atomicAdd(&cur[((uint32_t)idx[k].x) >> LOGSLICE], 1u);
        lrank[k * 4 + 1] = atomicAdd(&cur[((uint32_t)idx[k].y) >> LOGSLICE], 1u);
        lrank[k * 4 + 2] = atomicAdd(&cur[((uint32_t)idx[k].z) >> LOGSLICE], 1u);
        lrank[k * 4 + 3] = atomicAdd(&cur[((uint32_t)idx[k].w) >> LOGSLICE], 1u);
    }
    __syncthreads();

    // exclusive scan of per-bucket counts -> lstart (2 buckets/thread), wave shfl scan
    uint32_t c0 = cur[t * 2 + 0], c1 = cur[t * 2 + 1];
    uint32_t s = c0 + c1;
    uint32_t incl = s;
#pragma unroll
    for (int off = 1; off < 64; off <<= 1) {
        uint32_t u = __shfl_up(incl, off);
        if (lane >= off) incl += u;
    }
    if (lane == 63) wsum[w] = incl;
    __syncthreads();
    uint32_t woff = 0;
    for (int i = 0; i < w; ++i) woff += wsum[i];
    uint32_t ex = woff + incl - s;
    cur[t * 2 + 0] = ex;
    cur[t * 2 + 1] = ex + c0;
    __syncthreads();

    // place: slot = lstart[b] + lrank
#define PLACE(k, cc, e)                                                          \
    {                                                                            \
        uint32_t ix = (uint32_t)idx[k].cc;                                       \
        uint32_t b_ = ix >> LOGSLICE;                                            \
        uint32_t p_ = cur[b_] + lrank[e];                                        \
        spk[p_]  = (((uint32_t)val[k].cc) << LOGSLICE) | (ix & (SLICE - 1));     \
        sbid[p_] = (uint16_t)b_;                                                 \
    }
#pragma unroll
    for (int k = 0; k < EPT; ++k) {
        PLACE(k, x, k * 4 + 0) PLACE(k, y, k * 4 + 1)
        PLACE(k, z, k * 4 + 2) PLACE(k, w, k * 4 + 3)
    }
#undef PLACE
    __syncthreads();

    // cur[b] := doff[b] = bbase[b] + chunk_off[b] - lstart[b]  (addr = doff[b] + j)
#pragma unroll
    for (int r = 0; r < 2; ++r) {
        int i = t + r * BIN_THR;
        cur[i] = bbase[i] + gcnt[(size_t)c * NB + i] - cur[i];
    }
    __syncthreads();

    // write out: consecutive j within a bucket -> consecutive global addresses
#pragma unroll
    for (int k = 0; k < CHUNK / BIN_THR; ++k) {
        int j = t + k * BIN_THR;
        uint32_t b_ = sbid[j];
        pairs[cur[b_] + (uint32_t)j] = spk[j];
    }
}

// ---------- K5: per-slice LDS accumulate, out = input + acc ----------
__global__ __launch_bounds__(1024) void ip_accumulate(const uint32_t* __restrict__ pairs,
                                                      const uint32_t* __restrict__ btotal,
                                                      const uint32_t* __restrict__ bbase,
                                                      const int4* __restrict__ input4,
                                                      int4* __restrict__ out4) {
    __shared__ uint32_t acc[SLICE];    // 64 KiB
    const int t = threadIdx.x;
    // same XCD-chunked swizzle: adjacent buckets (adjacent pairs/input/out
    // regions) share an XCD L2.
    const int b = (int)((blockIdx.x & 7) * (gridDim.x >> 3) + (blockIdx.x >> 3));
    for (int j = t; j < SLICE; j += 1024) acc[j] = 0;
    __syncthreads();

    const uint32_t beg = bbase[b];
    const uint32_t cnt = btotal[b];

    uint32_t head = (4u - (beg & 3u)) & 3u;
    if (head > cnt) head = cnt;
    if (t < (int)head) {
        uint32_t pk = pairs[beg + t];
        atomicAdd(&acc[pk & (SLICE - 1)], pk >> LOGSLICE);
    }
    const uint32_t rem = cnt - head;
    const uint32_t n4  = rem >> 2;
    const uint32_t* __restrict__ p = pairs + beg + head;
    const uint4* __restrict__ p4 = (const uint4*)p;
    for (uint32_t j = t; j < n4; j += 1024) {
        uint4 pk = p4[j];
        atomicAdd(&acc[pk.x & (SLICE - 1)], pk.x >> LOGSLICE);
        atomicAdd(&acc[pk.y & (SLICE - 1)], pk.y >> LOGSLICE);
        atomicAdd(&acc[pk.z & (SLICE - 1)], pk.z >> LOGSLICE);
        atomicAdd(&acc[pk.w & (SLICE - 1)], pk.w >> LOGSLICE);
    }
    for (uint32_t j = (n4 << 2) + t; j < rem; j += 1024) {
        uint32_t pk = p[j];
        atomicAdd(&acc[pk & (SLICE - 1)], pk >> LOGSLICE);
    }
    __syncthreads();

    const int base4 = b * (SLICE / 4);
    for (int j = t; j < SLICE / 4; j += 1024) {
        int4 in = input4[base4 + j];
        in.x += (int)acc[j * 4 + 0];
        in.y += (int)acc[j * 4 + 1];
        in.z += (int)acc[j * 4 + 2];
        in.w += (int)acc[j * 4 + 3];
        out4[base4 + j] = in;
    }
}

// ---------- fallback: direct atomics ----------
__global__ void ip_copy_kernel(const int4* __restrict__ in, int4* __restrict__ out, int n4) {
    int stride = gridDim.x * blockDim.x;
    for (int i = blockIdx.x * blockDim.x + threadIdx.x; i < n4; i += stride)
        out[i] = in[i];
}
__global__ void ip_scatter1_kernel(const int* __restrict__ index, const int* __restrict__ value,
                                   int* __restrict__ out, int m) {
    int stride = gridDim.x * blockDim.x;
    for (int i = blockIdx.x * blockDim.x + threadIdx.x; i < m; i += stride)
        atomicAdd(&out[index[i]], value[i]);
}

extern "C" void kernel_launch(void* const* d_in, const int* in_sizes, int n_in,
                              void* d_out, int out_size, void* d_ws, size_t ws_size,
                              hipStream_t stream) {
    const int* input = (const int*)d_in[0];
    const int* index = (const int*)d_in[1];
    const int* value = (const int*)d_in[2];
    int* out = (int*)d_out;

    const int N = in_sizes[0];
    const int M = in_sizes[1];
    const int B = M / CHUNK;   // chunks (4096)

    const size_t gcnt_bytes = (size_t)B * NB * sizeof(uint32_t);      // 16 MB
    const size_t tot_bytes  = NB * sizeof(uint32_t);
    const size_t need = gcnt_bytes + 2 * tot_bytes + (size_t)M * sizeof(uint32_t);

    const bool ok = (N == NB * SLICE) && (M % CHUNK == 0) && (B % CNT_THR == 0) &&
                    (B % 8 == 0) && (ws_size >= need);

    if (ok) {
        uint32_t* gcnt   = (uint32_t*)d_ws;
        uint32_t* btotal = (uint32_t*)((char*)d_ws + gcnt_bytes);
        uint32_t* bbase  = btotal + NB;
        uint32_t* pairs  = bbase + NB;

        ip_count<<<B, CNT_THR, 0, stream>>>((const int4*)index, gcnt);
        ip_scan_chunks<<<NB, CNT_THR, 0, stream>>>(gcnt, btotal, B);
        ip_scan_buckets<<<1, NB, 0, stream>>>(btotal, bbase);
        ip_bin<<<B, BIN_THR, 0, stream>>>((const int4*)index, (const int4*)value,
                                          gcnt, bbase, pairs);
        ip_accumulate<<<NB, 1024, 0, stream>>>(pairs, btotal, bbase,
                                               (const int4*)input, (int4*)out);
    } else {
        ip_copy_kernel<<<2048, 256, 0, stream>>>((const int4*)input, (int4*)d_out, N / 4);
        ip_scatter1_kernel<<<2048, 256, 0, stream>>>(index, value, out, M);
    }
}

// Round 10
// 206.870 us; speedup vs baseline: 3.0846x; 1.1477x over previous
//
#include <hip/hip_runtime.h>
#include <stdint.h>

// out[index[i]] += value[i], duplicates accumulate. N = 2^24 table, M = 2^25 updates.
// Counting sort, no global atomics (capped ~26 G/s on gfx950, rounds 1-3).
// Round-10 = round-9 with the NT-builtin type fix: __builtin_nontemporal_* needs
// native clang vectors, not HIP_vector_type -> use ext_vector_type(4) int.
// scan_chunks: register-serial (16 chunks/thread) + wave shfl scan (2 barriers);
// XCD-chunked swizzles on bin/accumulate/scan (round 8: WRITE 247->145 MB).

#define LOGSLICE  14
#define SLICE     (1 << LOGSLICE)     // 16384 table entries per bucket (64 KiB acc)
#define NB        1024                // buckets = 2^24 / 2^14
#define CHUNK     8192                // updates per count/bin block
#define CNT_THR   256
#define BIN_THR   512
#define EPT       (CHUNK / 4 / BIN_THR)   // int4 loads per thread in bin = 4

typedef int  v4i __attribute__((ext_vector_type(4)));
typedef uint32_t v4u __attribute__((ext_vector_type(4)));

#define NTL(x)    __builtin_nontemporal_load(&(x))
#define NTS(p, v) __builtin_nontemporal_store((v), &(p))

// ---------- K1: per-chunk bucket histogram ----------
__global__ __launch_bounds__(256) void ip_count(const v4i* __restrict__ index4,
                                                uint32_t* __restrict__ gcnt) {
    __shared__ uint32_t cnt[NB];
    const int t = threadIdx.x, c = blockIdx.x;
    for (int i = t; i < NB; i += CNT_THR) cnt[i] = 0;
    __syncthreads();
    const int base4 = c * (CHUNK / 4);
#pragma unroll
    for (int k = 0; k < CHUNK / 4 / CNT_THR; ++k) {
        v4i id = NTL(index4[base4 + t + k * CNT_THR]);
        atomicAdd(&cnt[((uint32_t)id[0]) >> LOGSLICE], 1u);
        atomicAdd(&cnt[((uint32_t)id[1]) >> LOGSLICE], 1u);
        atomicAdd(&cnt[((uint32_t)id[2]) >> LOGSLICE], 1u);
        atomicAdd(&cnt[((uint32_t)id[3]) >> LOGSLICE], 1u);
    }
    __syncthreads();
    for (int i = t; i < NB; i += CNT_THR)
        gcnt[(size_t)c * NB + i] = cnt[i];
}

// ---------- K2: exclusive scan over chunks, per bucket ----------
// One block per bucket; thread t serially scans chunks 16t..16t+15 in registers,
// then wave-shfl scan of per-thread sums + one cross-wave LDS step.
#define SC_THR  256
#define SC_EPT  16        // chunks per thread (B must equal SC_THR*SC_EPT = 4096)
__global__ __launch_bounds__(256) void ip_scan_chunks(uint32_t* __restrict__ gcnt,
                                                      uint32_t* __restrict__ btotal) {
    __shared__ uint32_t wsum[SC_THR / 64];
    const int t = threadIdx.x;
    // XCD-grouped: consecutive buckets on the same XCD share gcnt cache lines.
    const int b = (int)((blockIdx.x & 7) * (gridDim.x >> 3) + (blockIdx.x >> 3));
    const int lane = t & 63, w = t >> 6;

    uint32_t v[SC_EPT];
#pragma unroll
    for (int k = 0; k < SC_EPT; ++k)
        v[k] = gcnt[(size_t)(t * SC_EPT + k) * NB + b];
    uint32_t s = 0;
#pragma unroll
    for (int k = 0; k < SC_EPT; ++k) { uint32_t x = v[k]; v[k] = s; s += x; }

    uint32_t incl = s;
#pragma unroll
    for (int off = 1; off < 64; off <<= 1) {
        uint32_t u = __shfl_up(incl, off);
        if (lane >= off) incl += u;
    }
    if (lane == 63) wsum[w] = incl;
    __syncthreads();
    uint32_t woff = 0;
    for (int i = 0; i < w; ++i) woff += wsum[i];
    const uint32_t base = woff + incl - s;   // exclusive prefix of this thread

#pragma unroll
    for (int k = 0; k < SC_EPT; ++k)
        gcnt[(size_t)(t * SC_EPT + k) * NB + b] = base + v[k];

    if (t == SC_THR - 1) btotal[b] = base + s;
}

// ---------- K3: exclusive scan over buckets ----------
__global__ __launch_bounds__(1024) void ip_scan_buckets(const uint32_t* __restrict__ btotal,
                                                        uint32_t* __restrict__ bbase) {
    __shared__ uint32_t tmp[NB];
    const int t = threadIdx.x;
    uint32_t v = btotal[t];
    tmp[t] = v; __syncthreads();
    for (int off = 1; off < NB; off <<= 1) {
        uint32_t u = (t >= off) ? tmp[t - off] : 0; __syncthreads();
        tmp[t] += u; __syncthreads();
    }
    bbase[t] = tmp[t] - v;
}

// ---------- K4: bin into bucket-contiguous runs via LDS staging ----------
__global__ __launch_bounds__(512) void ip_bin(const v4i* __restrict__ index4,
                                              const v4i* __restrict__ value4,
                                              const uint32_t* __restrict__ gcnt,
                                              const uint32_t* __restrict__ bbase,
                                              uint32_t* __restrict__ pairs) {
    __shared__ uint32_t cur[NB];        // counts -> lstart -> doff (reused in place)
    __shared__ uint32_t spk[CHUNK];     // staged payload, grouped by bucket (32 KiB)
    __shared__ uint16_t sbid[CHUNK];    // bucket id per staged slot (16 KiB)
    __shared__ uint32_t wsum[BIN_THR / 64];
    const int t = threadIdx.x;
    // XCD-chunked swizzle: consecutive chunks land on the same XCD's L2 so their
    // adjacent per-bucket run segments merge into full lines before writeback.
    const int c = (int)((blockIdx.x & 7) * (gridDim.x >> 3) + (blockIdx.x >> 3));
    const int lane = t & 63, w = t >> 6;

    cur[t * 2 + 0] = 0;
    cur[t * 2 + 1] = 0;
    __syncthreads();

    const int base4 = c * (CHUNK / 4);
    v4i idx[EPT], val[EPT];
#pragma unroll
    for (int k = 0; k < EPT; ++k) {
        idx[k] = NTL(index4[base4 + t + k * BIN_THR]);
        val[k] = NTL(value4[base4 + t + k * BIN_THR]);
    }
    uint32_t lrank[EPT * 4];
#pragma unroll
    for (int k = 0; k < EPT; ++k) {
        lrank[k * 4 + 0] = atomicAdd(&cur[((uint32_t)idx[k][0]) >> LOGSLICE], 1u);
        lrank[k * 4 + 1] = atomicAdd(&cur[((uint32_t)idx[k][1]) >> LOGSLICE], 1u);
        lrank[k * 4 + 2] = atomicAdd(&cur[((uint32_t)idx[k][2]) >> LOGSLICE], 1u);
        lrank[k * 4 + 3] = atomicAdd(&cur[((uint32_t)idx[k][3]) >> LOGSLICE], 1u);
    }
    __syncthreads();

    // exclusive scan of per-bucket counts -> lstart (2 buckets/thread), wave shfl scan
    uint32_t c0 = cur[t * 2 + 0], c1 = cur[t * 2 + 1];
    uint32_t s = c0 + c1;
    uint32_t incl = s;
#pragma unroll
    for (int off = 1; off < 64; off <<= 1) {
        uint32_t u = __shfl_up(incl, off);
        if (lane >= off) incl += u;
    }
    if (lane == 63) wsum[w] = incl;
    __syncthreads();
    uint32_t woff = 0;
    for (int i = 0; i < w; ++i) woff += wsum[i];
    uint32_t ex = woff + incl - s;
    cur[t * 2 + 0] = ex;
    cur[t * 2 + 1] = ex + c0;
    __syncthreads();

    // place: slot = lstart[b] + lrank
#define PLACE(k, cc, e)                                                          \
    {                                                                            \
        uint32_t ix = (uint32_t)idx[k][cc];                                      \
        uint32_t b_ = ix >> LOGSLICE;                                            \
        uint32_t p_ = cur[b_] + lrank[e];                                        \
        spk[p_]  = (((uint32_t)val[k][cc]) << LOGSLICE) | (ix & (SLICE - 1));    \
        sbid[p_] = (uint16_t)b_;                                                 \
    }
#pragma unroll
    for (int k = 0; k < EPT; ++k) {
        PLACE(k, 0, k * 4 + 0) PLACE(k, 1, k * 4 + 1)
        PLACE(k, 2, k * 4 + 2) PLACE(k, 3, k * 4 + 3)
    }
#undef PLACE
    __syncthreads();

    // cur[b] := doff[b] = bbase[b] + chunk_off[b] - lstart[b]  (addr = doff[b] + j)
#pragma unroll
    for (int r = 0; r < 2; ++r) {
        int i = t + r * BIN_THR;
        cur[i] = bbase[i] + gcnt[(size_t)c * NB + i] - cur[i];
    }
    __syncthreads();

    // write out: consecutive j within a bucket -> consecutive global addresses
#pragma unroll
    for (int k = 0; k < CHUNK / BIN_THR; ++k) {
        int j = t + k * BIN_THR;
        uint32_t b_ = sbid[j];
        pairs[cur[b_] + (uint32_t)j] = spk[j];
    }
}

// ---------- K5: per-slice LDS accumulate, out = input + acc ----------
__global__ __launch_bounds__(1024) void ip_accumulate(const uint32_t* __restrict__ pairs,
                                                      const uint32_t* __restrict__ btotal,
                                                      const uint32_t* __restrict__ bbase,
                                                      const v4i* __restrict__ input4,
                                                      v4i* __restrict__ out4) {
    __shared__ uint32_t acc[SLICE];    // 64 KiB
    const int t = threadIdx.x;
    // XCD-chunked swizzle: adjacent buckets (adjacent pairs/input/out regions)
    // share an XCD L2.
    const int b = (int)((blockIdx.x & 7) * (gridDim.x >> 3) + (blockIdx.x >> 3));
    for (int j = t; j < SLICE; j += 1024) acc[j] = 0;
    __syncthreads();

    const uint32_t beg = bbase[b];
    const uint32_t cnt = btotal[b];

    uint32_t head = (4u - (beg & 3u)) & 3u;
    if (head > cnt) head = cnt;
    if (t < (int)head) {
        uint32_t pk = pairs[beg + t];
        atomicAdd(&acc[pk & (SLICE - 1)], pk >> LOGSLICE);
    }
    const uint32_t rem = cnt - head;
    const uint32_t n4  = rem >> 2;
    const uint32_t* __restrict__ p = pairs + beg + head;
    const v4u* __restrict__ p4 = (const v4u*)p;
    for (uint32_t j = t; j < n4; j += 1024) {
        v4u pk = NTL(p4[j]);
        atomicAdd(&acc[pk[0] & (SLICE - 1)], pk[0] >> LOGSLICE);
        atomicAdd(&acc[pk[1] & (SLICE - 1)], pk[1] >> LOGSLICE);
        atomicAdd(&acc[pk[2] & (SLICE - 1)], pk[2] >> LOGSLICE);
        atomicAdd(&acc[pk[3] & (SLICE - 1)], pk[3] >> LOGSLICE);
    }
    for (uint32_t j = (n4 << 2) + t; j < rem; j += 1024) {
        uint32_t pk = p[j];
        atomicAdd(&acc[pk & (SLICE - 1)], pk >> LOGSLICE);
    }
    __syncthreads();

    const int base4 = b * (SLICE / 4);
    for (int j = t; j < SLICE / 4; j += 1024) {
        v4i in = NTL(input4[base4 + j]);
        in[0] += (int)acc[j * 4 + 0];
        in[1] += (int)acc[j * 4 + 1];
        in[2] += (int)acc[j * 4 + 2];
        in[3] += (int)acc[j * 4 + 3];
        NTS(out4[base4 + j], in);
    }
}

// ---------- fallback: direct atomics ----------
__global__ void ip_copy_kernel(const int4* __restrict__ in, int4* __restrict__ out, int n4) {
    int stride = gridDim.x * blockDim.x;
    for (int i = blockIdx.x * blockDim.x + threadIdx.x; i < n4; i += stride)
        out[i] = in[i];
}
__global__ void ip_scatter1_kernel(const int* __restrict__ index, const int* __restrict__ value,
                                   int* __restrict__ out, int m) {
    int stride = gridDim.x * blockDim.x;
    for (int i = blockIdx.x * blockDim.x + threadIdx.x; i < m; i += stride)
        atomicAdd(&out[index[i]], value[i]);
}

extern "C" void kernel_launch(void* const* d_in, const int* in_sizes, int n_in,
                              void* d_out, int out_size, void* d_ws, size_t ws_size,
                              hipStream_t stream) {
    const int* input = (const int*)d_in[0];
    const int* index = (const int*)d_in[1];
    const int* value = (const int*)d_in[2];
    int* out = (int*)d_out;

    const int N = in_sizes[0];
    const int M = in_sizes[1];
    const int B = M / CHUNK;   // chunks (4096)

    const size_t gcnt_bytes = (size_t)B * NB * sizeof(uint32_t);      // 16 MB
    const size_t tot_bytes  = NB * sizeof(uint32_t);
    const size_t need = gcnt_bytes + 2 * tot_bytes + (size_t)M * sizeof(uint32_t);

    const bool ok = (N == NB * SLICE) && (M % CHUNK == 0) && (B == SC_THR * SC_EPT) &&
                    (B % 8 == 0) && (ws_size >= need);

    if (ok) {
        uint32_t* gcnt   = (uint32_t*)d_ws;
        uint32_t* btotal = (uint32_t*)((char*)d_ws + gcnt_bytes);
        uint32_t* bbase  = btotal + NB;
        uint32_t* pairs  = bbase + NB;

        ip_count<<<B, CNT_THR, 0, stream>>>((const v4i*)index, gcnt);
        ip_scan_chunks<<<NB, SC_THR, 0, stream>>>(gcnt, btotal);
        ip_scan_buckets<<<1, NB, 0, stream>>>(btotal, bbase);
        ip_bin<<<B, BIN_THR, 0, stream>>>((const v4i*)index, (const v4i*)value,
                                          gcnt, bbase, pairs);
        ip_accumulate<<<NB, 1024, 0, stream>>>(pairs, btotal, bbase,
                                               (const v4i*)input, (v4i*)out);
    } else {
        ip_copy_kernel<<<2048, 256, 0, stream>>>((const int4*)input, (int4*)d_out, N / 4);
        ip_scatter1_kernel<<<2048, 256, 0, stream>>>(index, value, out, M);
    }
}